// Round 2
// baseline (2047.991 us; speedup 1.0000x reference)
//
#include <hip/hip_runtime.h>
#include <hip/hip_bf16.h>

typedef __bf16 bf16_t;
typedef __bf16 bf16x8 __attribute__((ext_vector_type(8)));
typedef __bf16 bf16x4 __attribute__((ext_vector_type(4)));
typedef float  f32x4  __attribute__((ext_vector_type(4)));

#define LDS_DST(p) ((__attribute__((address_space(3))) void*)(p))
#define GLB_SRC(p) ((const __attribute__((address_space(1))) void*)(p))

#define BM 128
#define BN 128
#define BK 64

// ---------------- fp32 -> bf16 convert (vectorized: float4 in, 4x bf16 out) ----
__global__ void __launch_bounds__(256)
f32_to_bf16_kernel(const float* __restrict__ in, bf16_t* __restrict__ out, int n4) {
  int i = blockIdx.x * 256 + threadIdx.x;
  if (i < n4) {
    const float4 v = reinterpret_cast<const float4*>(in)[i];
    bf16x4 o;
    o[0] = (bf16_t)v.x; o[1] = (bf16_t)v.y; o[2] = (bf16_t)v.z; o[3] = (bf16_t)v.w;
    reinterpret_cast<bf16x4*>(out)[i] = o;
  }
}

// ---------------- bf16 transpose: in [z][R][C] -> out [z][C][R] ----------------
__global__ void __launch_bounds__(256)
transpose_bf16_kernel(const bf16_t* __restrict__ in, bf16_t* __restrict__ out,
                      int R, int C) {
  __shared__ bf16_t tile[64][72];  // +8 pad: write-phase column reads spread banks
  const long base = (long)blockIdx.z * R * C;
  const bf16_t* ib = in + base;
  bf16_t* ob = out + base;
  const int r0 = blockIdx.x * 64, c0 = blockIdx.y * 64;
  const int tid = threadIdx.x;
  const int rr = tid >> 3, cg = tid & 7;
#pragma unroll
  for (int p = 0; p < 2; ++p) {
    int row = p * 32 + rr;
    bf16x8 v = *reinterpret_cast<const bf16x8*>(ib + (long)(r0 + row) * C + c0 + cg * 8);
    *reinterpret_cast<bf16x8*>(&tile[row][cg * 8]) = v;
  }
  __syncthreads();
#pragma unroll
  for (int p = 0; p < 2; ++p) {
    int c = p * 32 + rr;
    bf16x8 v;
#pragma unroll
    for (int i = 0; i < 8; ++i) v[i] = tile[cg * 8 + i][c];
    *reinterpret_cast<bf16x8*>(ob + (long)(c0 + c) * R + r0 + cg * 8) = v;
  }
}

// ---------------- GEMM, both operands K-contiguous ("B^T input") ---------------
// C[m][n] = sum_k A[m][k]*B[n][k]  (+bias / mask+sigmoid / plain fp32 per MODE)
// MODE 0: bf16 out = acc + bias[n]
// MODE 1: bf16 out = mask ? sigmoid(acc) : 0
// MODE 2: f32 out  = acc
// m97 structure main loop; epilogue rearranged through LDS for coalesced I/O.
template <int MODE>
__global__ void __launch_bounds__(256)
gemm_bt_kernel(const bf16_t* __restrict__ A, const bf16_t* __restrict__ B,
               const float* __restrict__ bias, const int* __restrict__ mask,
               void* __restrict__ Cout, int M, int N, int K,
               long sA, long sB, long sC, long sMask) {
  __shared__ char smem[BM * BK * 2 + BN * BK * 2];  // 32 KiB
  char* As = smem;
  char* Bs = smem + BM * BK * 2;
  const int bz = blockIdx.z;
  const bf16_t* Ab = A + bz * sA;
  const bf16_t* Bb = B + bz * sB;
  const int bm = blockIdx.x * BM;
  const int bn = blockIdx.y * BN;
  const int tid = threadIdx.x;
  const int wave = tid >> 6, lane = tid & 63;
  const int wr = wave >> 1, wc = wave & 1;
  f32x4 acc[4][4] = {};

  for (int k0 = 0; k0 < K; k0 += BK) {
    // stage A/B tiles [128][64] bf16: linear LDS dest, source column-group XORed
    // so the swizzled ds_read below sees the right data (rule #21).
#pragma unroll
    for (int j = 0; j < 4; ++j) {
      int c = j * 256 + tid;
      int row = c >> 3;
      int cgs = (c & 7) ^ (row & 7);
      __builtin_amdgcn_global_load_lds(
          GLB_SRC(Ab + (long)(bm + row) * K + k0 + cgs * 8),
          LDS_DST(As + (j * 256 + wave * 64) * 16), 16, 0, 0);
    }
#pragma unroll
    for (int j = 0; j < 4; ++j) {
      int c = j * 256 + tid;
      int row = c >> 3;
      int cgs = (c & 7) ^ (row & 7);
      __builtin_amdgcn_global_load_lds(
          GLB_SRC(Bb + (long)(bn + row) * K + k0 + cgs * 8),
          LDS_DST(Bs + (j * 256 + wave * 64) * 16), 16, 0, 0);
    }
    __syncthreads();

#pragma unroll
    for (int kk = 0; kk < 2; ++kk) {
      bf16x8 af[4], bfr[4];
#pragma unroll
      for (int t = 0; t < 4; ++t) {
        int ra = wr * 64 + t * 16 + (lane & 15);
        int ca = (kk * 64 + (lane >> 4) * 16) ^ ((ra & 7) << 4);
        af[t] = *reinterpret_cast<const bf16x8*>(As + ra * 128 + ca);
        int rb = wc * 64 + t * 16 + (lane & 15);
        int cb = (kk * 64 + (lane >> 4) * 16) ^ ((rb & 7) << 4);
        bfr[t] = *reinterpret_cast<const bf16x8*>(Bs + rb * 128 + cb);
      }
#pragma unroll
      for (int mt = 0; mt < 4; ++mt)
#pragma unroll
        for (int nt = 0; nt < 4; ++nt)
          acc[mt][nt] = __builtin_amdgcn_mfma_f32_16x16x32_bf16(
              af[mt], bfr[nt], acc[mt][nt], 0, 0, 0);
    }
    __syncthreads();
  }

  // ---- epilogue: LDS rearrange (32x128 f32 chunk, col-XOR swizzle) ----
  // 4 rounds; per round, the 2 waves owning the 32 output rows write their acc
  // into LDS; then all 256 threads stream it out coalesced (row = tid>>3,
  // 16 contiguous cols = tid&7). Mask/bias loads become 16B vector loads.
  float* eb = (float*)smem;  // 16 KiB used
  const int tid8 = tid & 7;
  const int trow = tid >> 3;
#pragma unroll 1
  for (int round = 0; round < 4; ++round) {
    const int wr_c = round >> 1, mtb = (round & 1) * 2;
    __syncthreads();
    if (wr == wr_c) {
#pragma unroll
      for (int mi = 0; mi < 2; ++mi) {
#pragma unroll
        for (int nt = 0; nt < 4; ++nt) {
          const int col = wc * 64 + nt * 16 + (lane & 15);
#pragma unroll
          for (int r = 0; r < 4; ++r) {
            const int row = mi * 16 + ((lane >> 4) << 2) + r;  // 0..31 in chunk
            eb[row * 128 + (col ^ ((row & 7) << 2))] = acc[mtb + mi][nt][r];
          }
        }
      }
    }
    __syncthreads();
    const int grow = bm + wr_c * 64 + mtb * 16 + trow;
    const long rowoff = (long)grow * N + bn + tid8 * 16;
    float vals[16];
#pragma unroll
    for (int j = 0; j < 4; ++j) {
      const int c = tid8 * 16 + j * 4;
      const f32x4 v = *reinterpret_cast<const f32x4*>(
          &eb[trow * 128 + (c ^ ((trow & 7) << 2))]);
      vals[j * 4 + 0] = v[0]; vals[j * 4 + 1] = v[1];
      vals[j * 4 + 2] = v[2]; vals[j * 4 + 3] = v[3];
    }
    if constexpr (MODE == 0) {
      float bvs[16];
#pragma unroll
      for (int j = 0; j < 4; ++j) {
        const f32x4 b4 = *reinterpret_cast<const f32x4*>(bias + bn + tid8 * 16 + j * 4);
        bvs[j * 4 + 0] = b4[0]; bvs[j * 4 + 1] = b4[1];
        bvs[j * 4 + 2] = b4[2]; bvs[j * 4 + 3] = b4[3];
      }
      bf16x8 o0, o1;
#pragma unroll
      for (int e = 0; e < 8; ++e) {
        o0[e] = (bf16_t)(vals[e] + bvs[e]);
        o1[e] = (bf16_t)(vals[8 + e] + bvs[8 + e]);
      }
      bf16_t* C = (bf16_t*)Cout + bz * sC;
      *reinterpret_cast<bf16x8*>(C + rowoff) = o0;
      *reinterpret_cast<bf16x8*>(C + rowoff + 8) = o1;
    } else if constexpr (MODE == 1) {
      int mv[16];
#pragma unroll
      for (int j = 0; j < 4; ++j) {
        const int4 m4 = *reinterpret_cast<const int4*>(mask + bz * sMask + rowoff + j * 4);
        mv[j * 4 + 0] = m4.x; mv[j * 4 + 1] = m4.y;
        mv[j * 4 + 2] = m4.z; mv[j * 4 + 3] = m4.w;
      }
      bf16x8 o0, o1;
#pragma unroll
      for (int e = 0; e < 16; ++e) {
        const float p = mv[e] ? __builtin_amdgcn_rcpf(1.f + __expf(-vals[e])) : 0.f;
        if (e < 8) o0[e] = (bf16_t)p; else o1[e - 8] = (bf16_t)p;
      }
      bf16_t* C = (bf16_t*)Cout + bz * sC;
      *reinterpret_cast<bf16x8*>(C + rowoff) = o0;
      *reinterpret_cast<bf16x8*>(C + rowoff + 8) = o1;
    } else {
      float* C = (float*)Cout + bz * sC;
#pragma unroll
      for (int j = 0; j < 4; ++j)
        *reinterpret_cast<f32x4*>(C + rowoff + j * 4) =
            *reinterpret_cast<const f32x4*>(&vals[j * 4]);
    }
  }
}

extern "C" void kernel_launch(void* const* d_in, const int* in_sizes, int n_in,
                              void* d_out, int out_size, void* d_ws, size_t ws_size,
                              hipStream_t stream) {
  const float* queries = (const float*)d_in[0];
  const float* values  = (const float*)d_in[1];
  const int*   mask    = (const int*)d_in[2];
  const float* Wq = (const float*)d_in[3];
  const float* bq = (const float*)d_in[4];
  const float* Wk = (const float*)d_in[5];
  const float* bk = (const float*)d_in[6];
  const float* Wv = (const float*)d_in[7];
  const float* bv = (const float*)d_in[8];

  // B=8, L=2048, D=768. Workspace layout (bytes):
  char* ws = (char*)d_ws;
  bf16_t* qb  = (bf16_t*)(ws + 0);          // queries bf16   25165824
  bf16_t* vb  = (bf16_t*)(ws + 25165824);   // values bf16    25165824
  bf16_t* wqb = (bf16_t*)(ws + 50331648);   // Wq bf16         1179648
  bf16_t* wkb = (bf16_t*)(ws + 51511296);   // Wk bf16         1179648
  bf16_t* wvb = (bf16_t*)(ws + 52690944);   // Wv bf16         1179648
  bf16_t* qp  = (bf16_t*)(ws + 53870592);   // q_proj         25165824
  bf16_t* vp  = (bf16_t*)(ws + 79036416);   // v_proj         25165824
  bf16_t* kp  = (bf16_t*)(ws + 104202240);  // k_proj         25165824
  bf16_t* vpT = (bf16_t*)(ws + 129368064);  // v_proj^T       25165824
  bf16_t* P   = (bf16_t*)(ws + 154533888);  // sigmoid scores 67108864
  // total: 221642752 bytes

  const dim3 blk(256);

  // converts
  f32_to_bf16_kernel<<<12288, blk, 0, stream>>>(queries, qb, 3145728);
  f32_to_bf16_kernel<<<12288, blk, 0, stream>>>(values, vb, 3145728);
  f32_to_bf16_kernel<<<576, blk, 0, stream>>>(Wq, wqb, 147456);
  f32_to_bf16_kernel<<<576, blk, 0, stream>>>(Wk, wkb, 147456);
  f32_to_bf16_kernel<<<576, blk, 0, stream>>>(Wv, wvb, 147456);

  // projections: [16384,768] x W[768,768]^T + b -> bf16
  gemm_bt_kernel<0><<<dim3(128, 6, 1), blk, 0, stream>>>(
      qb, wqb, bq, nullptr, qp, 16384, 768, 768, 0, 0, 0, 0);
  gemm_bt_kernel<0><<<dim3(128, 6, 1), blk, 0, stream>>>(
      vb, wvb, bv, nullptr, vp, 16384, 768, 768, 0, 0, 0, 0);
  // NOTE faithful quirk: k = Linear_k(v_proj)
  gemm_bt_kernel<0><<<dim3(128, 6, 1), blk, 0, stream>>>(
      vp, wkb, bk, nullptr, kp, 16384, 768, 768, 0, 0, 0, 0);

  // v_proj [b][2048][768] -> v_projT [b][768][2048]
  transpose_bf16_kernel<<<dim3(32, 12, 8), blk, 0, stream>>>(vp, vpT, 2048, 768);

  // P = sigmoid(mask(q k^T)) : per batch [2048,2048], K=768
  gemm_bt_kernel<1><<<dim3(16, 16, 8), blk, 0, stream>>>(
      qp, kp, nullptr, mask, P, 2048, 2048, 768,
      (long)2048 * 768, (long)2048 * 768, (long)2048 * 2048, (long)2048 * 2048);

  // context = P v : per batch [2048,768], K=2048, fp32 out
  gemm_bt_kernel<2><<<dim3(16, 6, 8), blk, 0, stream>>>(
      P, vpT, nullptr, nullptr, d_out, 2048, 768, 2048,
      (long)2048 * 2048, (long)768 * 2048, (long)2048 * 768, 0);
}

// Round 3
// 365.508 us; speedup vs baseline: 5.6031x; 5.6031x over previous
//
#include <hip/hip_runtime.h>
#include <hip/hip_bf16.h>

typedef __bf16 bf16_t;
typedef __bf16 bf16x8 __attribute__((ext_vector_type(8)));
typedef __bf16 bf16x4 __attribute__((ext_vector_type(4)));
typedef float  f32x4  __attribute__((ext_vector_type(4)));

#define LDS_DST(p) ((__attribute__((address_space(3))) void*)(p))
#define GLB_SRC(p) ((const __attribute__((address_space(1))) void*)(p))

#define BM 128
#define BN 128
#define BK 64

// ---------------- fp32 -> bf16 convert (vectorized: float4 in, 4x bf16 out) ----
__global__ void __launch_bounds__(256)
f32_to_bf16_kernel(const float* __restrict__ in, bf16_t* __restrict__ out, int n4) {
  int i = blockIdx.x * 256 + threadIdx.x;
  if (i < n4) {
    const float4 v = reinterpret_cast<const float4*>(in)[i];
    bf16x4 o;
    o[0] = (bf16_t)v.x; o[1] = (bf16_t)v.y; o[2] = (bf16_t)v.z; o[3] = (bf16_t)v.w;
    reinterpret_cast<bf16x4*>(out)[i] = o;
  }
}

// ---------------- bf16 transpose: in [z][R][C] -> out [z][C][R] ----------------
__global__ void __launch_bounds__(256)
transpose_bf16_kernel(const bf16_t* __restrict__ in, bf16_t* __restrict__ out,
                      int R, int C) {
  __shared__ bf16_t tile[64][72];  // +8 pad: write-phase column reads spread banks
  const long base = (long)blockIdx.z * R * C;
  const bf16_t* ib = in + base;
  bf16_t* ob = out + base;
  const int r0 = blockIdx.x * 64, c0 = blockIdx.y * 64;
  const int tid = threadIdx.x;
  const int rr = tid >> 3, cg = tid & 7;
#pragma unroll
  for (int p = 0; p < 2; ++p) {
    int row = p * 32 + rr;
    bf16x8 v = *reinterpret_cast<const bf16x8*>(ib + (long)(r0 + row) * C + c0 + cg * 8);
    *reinterpret_cast<bf16x8*>(&tile[row][cg * 8]) = v;
  }
  __syncthreads();
#pragma unroll
  for (int p = 0; p < 2; ++p) {
    int c = p * 32 + rr;
    bf16x8 v;
#pragma unroll
    for (int i = 0; i < 8; ++i) v[i] = tile[cg * 8 + i][c];
    *reinterpret_cast<bf16x8*>(ob + (long)(c0 + c) * R + r0 + cg * 8) = v;
  }
}

// ---------------- GEMM, both operands K-contiguous ("B^T input") ---------------
// C[m][n] = sum_k A[m][k]*B[n][k]  (+bias / mask+sigmoid / plain fp32 per MODE)
// MODE 0: bf16 out = acc + bias[n]
// MODE 1: bf16 out = mask ? sigmoid(acc) : 0
// MODE 2: f32 out  = acc
// m97 structure main loop; epilogue rearranged through LDS for coalesced I/O.
template <int MODE>
__global__ void __launch_bounds__(256)
gemm_bt_kernel(const bf16_t* __restrict__ A, const bf16_t* __restrict__ B,
               const float* __restrict__ bias, const int* __restrict__ mask,
               void* __restrict__ Cout, int M, int N, int K,
               long sA, long sB, long sC, long sMask) {
  __shared__ char smem[BM * BK * 2 + BN * BK * 2];  // 32 KiB
  char* As = smem;
  char* Bs = smem + BM * BK * 2;
  const int bz = blockIdx.z;
  const bf16_t* Ab = A + bz * sA;
  const bf16_t* Bb = B + bz * sB;
  const int bm = blockIdx.x * BM;
  const int bn = blockIdx.y * BN;
  const int tid = threadIdx.x;
  const int wave = tid >> 6, lane = tid & 63;
  const int wr = wave >> 1, wc = wave & 1;
  f32x4 acc[4][4] = {};

  for (int k0 = 0; k0 < K; k0 += BK) {
    // stage A/B tiles [128][64] bf16: linear LDS dest, source column-group XORed
    // so the swizzled ds_read below sees the right data (rule #21).
#pragma unroll
    for (int j = 0; j < 4; ++j) {
      int c = j * 256 + tid;
      int row = c >> 3;
      int cgs = (c & 7) ^ (row & 7);
      __builtin_amdgcn_global_load_lds(
          GLB_SRC(Ab + (long)(bm + row) * K + k0 + cgs * 8),
          LDS_DST(As + (j * 256 + wave * 64) * 16), 16, 0, 0);
    }
#pragma unroll
    for (int j = 0; j < 4; ++j) {
      int c = j * 256 + tid;
      int row = c >> 3;
      int cgs = (c & 7) ^ (row & 7);
      __builtin_amdgcn_global_load_lds(
          GLB_SRC(Bb + (long)(bn + row) * K + k0 + cgs * 8),
          LDS_DST(Bs + (j * 256 + wave * 64) * 16), 16, 0, 0);
    }
    __syncthreads();

#pragma unroll
    for (int kk = 0; kk < 2; ++kk) {
      bf16x8 af[4], bfr[4];
#pragma unroll
      for (int t = 0; t < 4; ++t) {
        int ra = wr * 64 + t * 16 + (lane & 15);
        int ca = (kk * 64 + (lane >> 4) * 16) ^ ((ra & 7) << 4);
        af[t] = *reinterpret_cast<const bf16x8*>(As + ra * 128 + ca);
        int rb = wc * 64 + t * 16 + (lane & 15);
        int cb = (kk * 64 + (lane >> 4) * 16) ^ ((rb & 7) << 4);
        bfr[t] = *reinterpret_cast<const bf16x8*>(Bs + rb * 128 + cb);
      }
#pragma unroll
      for (int mt = 0; mt < 4; ++mt)
#pragma unroll
        for (int nt = 0; nt < 4; ++nt)
          acc[mt][nt] = __builtin_amdgcn_mfma_f32_16x16x32_bf16(
              af[mt], bfr[nt], acc[mt][nt], 0, 0, 0);
    }
    __syncthreads();
  }

  // ---- epilogue: LDS rearrange (32x128 f32 chunk, col-XOR swizzle) ----
  // 4 rounds; per round, the 2 waves owning the 32 output rows write their acc
  // into LDS; then all 256 threads stream it out coalesced (row = tid>>3,
  // 16 contiguous cols = tid&7). Mask/bias loads become 16B vector loads.
  //
  // NOTE: this loop MUST be fully unrolled. `#pragma unroll 1` here (round 2)
  // made `mtb` runtime -> acc[] runtime-indexed -> entire accumulator demoted
  // to scratch (rule #20): WRITE_SIZE 118MB -> 2.3GB, 3x slowdown.
  float* eb = (float*)smem;  // 16 KiB used
  const int tid8 = tid & 7;
  const int trow = tid >> 3;
#pragma unroll
  for (int round = 0; round < 4; ++round) {
    const int wr_c = round >> 1, mtb = (round & 1) * 2;
    __syncthreads();
    if (wr == wr_c) {
#pragma unroll
      for (int mi = 0; mi < 2; ++mi) {
#pragma unroll
        for (int nt = 0; nt < 4; ++nt) {
          const int col = wc * 64 + nt * 16 + (lane & 15);
#pragma unroll
          for (int r = 0; r < 4; ++r) {
            const int row = mi * 16 + ((lane >> 4) << 2) + r;  // 0..31 in chunk
            eb[row * 128 + (col ^ ((row & 7) << 2))] = acc[mtb + mi][nt][r];
          }
        }
      }
    }
    __syncthreads();
    const int grow = bm + wr_c * 64 + mtb * 16 + trow;
    const long rowoff = (long)grow * N + bn + tid8 * 16;
    float vals[16];
#pragma unroll
    for (int j = 0; j < 4; ++j) {
      const int c = tid8 * 16 + j * 4;
      const f32x4 v = *reinterpret_cast<const f32x4*>(
          &eb[trow * 128 + (c ^ ((trow & 7) << 2))]);
      vals[j * 4 + 0] = v[0]; vals[j * 4 + 1] = v[1];
      vals[j * 4 + 2] = v[2]; vals[j * 4 + 3] = v[3];
    }
    if constexpr (MODE == 0) {
      float bvs[16];
#pragma unroll
      for (int j = 0; j < 4; ++j) {
        const f32x4 b4 = *reinterpret_cast<const f32x4*>(bias + bn + tid8 * 16 + j * 4);
        bvs[j * 4 + 0] = b4[0]; bvs[j * 4 + 1] = b4[1];
        bvs[j * 4 + 2] = b4[2]; bvs[j * 4 + 3] = b4[3];
      }
      bf16x8 o0, o1;
#pragma unroll
      for (int e = 0; e < 8; ++e) {
        o0[e] = (bf16_t)(vals[e] + bvs[e]);
        o1[e] = (bf16_t)(vals[8 + e] + bvs[8 + e]);
      }
      bf16_t* C = (bf16_t*)Cout + bz * sC;
      *reinterpret_cast<bf16x8*>(C + rowoff) = o0;
      *reinterpret_cast<bf16x8*>(C + rowoff + 8) = o1;
    } else if constexpr (MODE == 1) {
      int mv[16];
#pragma unroll
      for (int j = 0; j < 4; ++j) {
        const int4 m4 = *reinterpret_cast<const int4*>(mask + bz * sMask + rowoff + j * 4);
        mv[j * 4 + 0] = m4.x; mv[j * 4 + 1] = m4.y;
        mv[j * 4 + 2] = m4.z; mv[j * 4 + 3] = m4.w;
      }
      bf16x8 o0, o1;
#pragma unroll
      for (int e = 0; e < 16; ++e) {
        const float p = mv[e] ? __builtin_amdgcn_rcpf(1.f + __expf(-vals[e])) : 0.f;
        if (e < 8) o0[e] = (bf16_t)p; else o1[e - 8] = (bf16_t)p;
      }
      bf16_t* C = (bf16_t*)Cout + bz * sC;
      *reinterpret_cast<bf16x8*>(C + rowoff) = o0;
      *reinterpret_cast<bf16x8*>(C + rowoff + 8) = o1;
    } else {
      float* C = (float*)Cout + bz * sC;
#pragma unroll
      for (int j = 0; j < 4; ++j)
        *reinterpret_cast<f32x4*>(C + rowoff + j * 4) =
            *reinterpret_cast<const f32x4*>(&vals[j * 4]);
    }
  }
}

extern "C" void kernel_launch(void* const* d_in, const int* in_sizes, int n_in,
                              void* d_out, int out_size, void* d_ws, size_t ws_size,
                              hipStream_t stream) {
  const float* queries = (const float*)d_in[0];
  const float* values  = (const float*)d_in[1];
  const int*   mask    = (const int*)d_in[2];
  const float* Wq = (const float*)d_in[3];
  const float* bq = (const float*)d_in[4];
  const float* Wk = (const float*)d_in[5];
  const float* bk = (const float*)d_in[6];
  const float* Wv = (const float*)d_in[7];
  const float* bv = (const float*)d_in[8];

  // B=8, L=2048, D=768. Workspace layout (bytes):
  char* ws = (char*)d_ws;
  bf16_t* qb  = (bf16_t*)(ws + 0);          // queries bf16   25165824
  bf16_t* vb  = (bf16_t*)(ws + 25165824);   // values bf16    25165824
  bf16_t* wqb = (bf16_t*)(ws + 50331648);   // Wq bf16         1179648
  bf16_t* wkb = (bf16_t*)(ws + 51511296);   // Wk bf16         1179648
  bf16_t* wvb = (bf16_t*)(ws + 52690944);   // Wv bf16         1179648
  bf16_t* qp  = (bf16_t*)(ws + 53870592);   // q_proj         25165824
  bf16_t* vp  = (bf16_t*)(ws + 79036416);   // v_proj         25165824
  bf16_t* kp  = (bf16_t*)(ws + 104202240);  // k_proj         25165824
  bf16_t* vpT = (bf16_t*)(ws + 129368064);  // v_proj^T       25165824
  bf16_t* P   = (bf16_t*)(ws + 154533888);  // sigmoid scores 67108864
  // total: 221642752 bytes

  const dim3 blk(256);

  // converts
  f32_to_bf16_kernel<<<12288, blk, 0, stream>>>(queries, qb, 3145728);
  f32_to_bf16_kernel<<<12288, blk, 0, stream>>>(values, vb, 3145728);
  f32_to_bf16_kernel<<<576, blk, 0, stream>>>(Wq, wqb, 147456);
  f32_to_bf16_kernel<<<576, blk, 0, stream>>>(Wk, wkb, 147456);
  f32_to_bf16_kernel<<<576, blk, 0, stream>>>(Wv, wvb, 147456);

  // projections: [16384,768] x W[768,768]^T + b -> bf16
  gemm_bt_kernel<0><<<dim3(128, 6, 1), blk, 0, stream>>>(
      qb, wqb, bq, nullptr, qp, 16384, 768, 768, 0, 0, 0, 0);
  gemm_bt_kernel<0><<<dim3(128, 6, 1), blk, 0, stream>>>(
      vb, wvb, bv, nullptr, vp, 16384, 768, 768, 0, 0, 0, 0);
  // NOTE faithful quirk: k = Linear_k(v_proj)
  gemm_bt_kernel<0><<<dim3(128, 6, 1), blk, 0, stream>>>(
      vp, wkb, bk, nullptr, kp, 16384, 768, 768, 0, 0, 0, 0);

  // v_proj [b][2048][768] -> v_projT [b][768][2048]
  transpose_bf16_kernel<<<dim3(32, 12, 8), blk, 0, stream>>>(vp, vpT, 2048, 768);

  // P = sigmoid(mask(q k^T)) : per batch [2048,2048], K=768
  gemm_bt_kernel<1><<<dim3(16, 16, 8), blk, 0, stream>>>(
      qp, kp, nullptr, mask, P, 2048, 2048, 768,
      (long)2048 * 768, (long)2048 * 768, (long)2048 * 2048, (long)2048 * 2048);

  // context = P v : per batch [2048,768], K=2048, fp32 out
  gemm_bt_kernel<2><<<dim3(16, 6, 8), blk, 0, stream>>>(
      P, vpT, nullptr, nullptr, d_out, 2048, 768, 2048,
      (long)2048 * 2048, (long)768 * 2048, (long)2048 * 768, 0);
}

// Round 4
// 306.922 us; speedup vs baseline: 6.6727x; 1.1909x over previous
//
#include <hip/hip_runtime.h>
#include <hip/hip_bf16.h>

typedef __bf16 bf16_t;
typedef __bf16 bf16x8 __attribute__((ext_vector_type(8)));
typedef __bf16 bf16x4 __attribute__((ext_vector_type(4)));
typedef float  f32x4  __attribute__((ext_vector_type(4)));

#define LDS_DST(p) ((__attribute__((address_space(3))) void*)(p))
#define GLB_SRC(p) ((const __attribute__((address_space(1))) void*)(p))

#define SBAR()   asm volatile("s_barrier" ::: "memory")
#define WLGKM0() asm volatile("s_waitcnt lgkmcnt(0)" ::: "memory")
#define WVM6()   asm volatile("s_waitcnt vmcnt(6)" ::: "memory")
#define WVM0()   asm volatile("s_waitcnt vmcnt(0)" ::: "memory")

// ---------------- fp32 -> bf16 convert ----------------
__global__ void __launch_bounds__(256)
f32_to_bf16_kernel(const float* __restrict__ in, bf16_t* __restrict__ out, int n4) {
  int i = blockIdx.x * 256 + threadIdx.x;
  if (i < n4) {
    const float4 v = reinterpret_cast<const float4*>(in)[i];
    bf16x4 o;
    o[0] = (bf16_t)v.x; o[1] = (bf16_t)v.y; o[2] = (bf16_t)v.z; o[3] = (bf16_t)v.w;
    reinterpret_cast<bf16x4*>(out)[i] = o;
  }
}

// ---------------- bf16 transpose: in [z][R][C] -> out [z][C][R] ----------------
__global__ void __launch_bounds__(256)
transpose_bf16_kernel(const bf16_t* __restrict__ in, bf16_t* __restrict__ out,
                      int R, int C) {
  __shared__ bf16_t tile[64][72];
  const long base = (long)blockIdx.z * R * C;
  const bf16_t* ib = in + base;
  bf16_t* ob = out + base;
  const int r0 = blockIdx.x * 64, c0 = blockIdx.y * 64;
  const int tid = threadIdx.x;
  const int rr = tid >> 3, cg = tid & 7;
#pragma unroll
  for (int p = 0; p < 2; ++p) {
    int row = p * 32 + rr;
    bf16x8 v = *reinterpret_cast<const bf16x8*>(ib + (long)(r0 + row) * C + c0 + cg * 8);
    *reinterpret_cast<bf16x8*>(&tile[row][cg * 8]) = v;
  }
  __syncthreads();
#pragma unroll
  for (int p = 0; p < 2; ++p) {
    int c = p * 32 + rr;
    bf16x8 v;
#pragma unroll
    for (int i = 0; i < 8; ++i) v[i] = tile[cg * 8 + i][c];
    *reinterpret_cast<bf16x8*>(ob + (long)(c0 + c) * R + r0 + cg * 8) = v;
  }
}

// ================= 256x256 8-phase GEMM (T2+T3+T4+T5) =================
// C[m][n] = sum_k A[m][k]*B[n][k], both operands K-contiguous.
// 512 thr / 8 waves (2Mx4N), BK=64, LDS 2 slots x (A 32KB + B 32KB) = 128KB.
// Stageable units (16KB each, 16x1KB wave-chunks):
//   A-half mh: rows {mh*64..+64} u {128+mh*64..+64}   (read only at phases with that mh)
//   B-half nh: rows {wc*64+nh*32..+32 for wc=0..3}    (read only at phases with that nh)
// Quadrant order per tile: (0,0),(0,1),(1,1),(1,0); A/B frag regs reused across
// adjacent phases; B0 re-read at P4 (caps frag pressure at 12 frags).
// Staging map (phase p stages the region last read at p-1, 2 tiles ahead):
//   P1: B0(t+1->s1)  P2: A0(t+2->s0)  P3: B1(t+2->s0)  P4: A1(t+2->s0) vmcnt(6)
//   P5: B0(t+2->s0)  P6: A0(t+3->s1)  P7: B1(t+3->s1)  P8: A1(t+3->s1) vmcnt(6)
// vmcnt(6)+barrier at P4/P8 => all stages >=3 phases old have landed for ALL waves.

__device__ __forceinline__ void stage_A(char* smem, const bf16_t* G, int ldK,
                                        int grow0, int slot, int mh, int kt, int tid) {
  const int wave = tid >> 6, l = tid & 63;
  const int lr = l >> 3;                    // row within 8-row chunk
  const int cgs = ((l & 7) ^ lr) * 8;       // pre-swizzled source col-group (rule #21)
#pragma unroll
  for (int j = 0; j < 2; ++j) {
    const int rowbase = j * 128 + mh * 64 + wave * 8;
    __builtin_amdgcn_global_load_lds(
        GLB_SRC(G + (long)(grow0 + rowbase + lr) * ldK + kt + cgs),
        LDS_DST(smem + slot * 65536 + rowbase * 128), 16, 0, 0);
  }
}

__device__ __forceinline__ void stage_B(char* smem, const bf16_t* G, int ldK,
                                        int grow0, int slot, int nh, int kt, int tid) {
  const int wave = tid >> 6, l = tid & 63;
  const int lr = l >> 3;
  const int cgs = ((l & 7) ^ lr) * 8;
#pragma unroll
  for (int j = 0; j < 2; ++j) {
    const int c = wave + j * 8;             // chunk 0..15 -> band c>>2, sub c&3
    const int rowbase = (c >> 2) * 64 + nh * 32 + (c & 3) * 8;
    __builtin_amdgcn_global_load_lds(
        GLB_SRC(G + (long)(grow0 + rowbase + lr) * ldK + kt + cgs),
        LDS_DST(smem + slot * 65536 + 32768 + rowbase * 128), 16, 0, 0);
  }
}

__device__ __forceinline__ void read_A(const char* smem, int off, bf16x8 (&af)[8], int xk0) {
#pragma unroll
  for (int mf = 0; mf < 4; ++mf)
#pragma unroll
    for (int kk = 0; kk < 2; ++kk)
      af[mf * 2 + kk] = *reinterpret_cast<const bf16x8*>(
          smem + off + mf * 2048 + (kk ? (xk0 ^ 64) : xk0));
}

__device__ __forceinline__ void read_B(const char* smem, int off, bf16x8 (&bf_)[4], int xk0) {
#pragma unroll
  for (int nf = 0; nf < 2; ++nf)
#pragma unroll
    for (int kk = 0; kk < 2; ++kk)
      bf_[nf * 2 + kk] = *reinterpret_cast<const bf16x8*>(
          smem + off + nf * 2048 + (kk ? (xk0 ^ 64) : xk0));
}

template <int MH, int NH>
__device__ __forceinline__ void mfma_q(const bf16x8 (&af)[8], const bf16x8 (&bf_)[4],
                                       f32x4 (&acc)[8][4]) {
#pragma unroll
  for (int mf = 0; mf < 4; ++mf)
#pragma unroll
    for (int nf = 0; nf < 2; ++nf)
#pragma unroll
      for (int kk = 0; kk < 2; ++kk)
        acc[MH * 4 + mf][NH * 2 + nf] = __builtin_amdgcn_mfma_f32_16x16x32_bf16(
            af[mf * 2 + kk], bf_[nf * 2 + kk], acc[MH * 4 + mf][NH * 2 + nf], 0, 0, 0);
}

#define PH_MID() do { SBAR(); WLGKM0(); __builtin_amdgcn_s_setprio(1); } while (0)
#define PH_END() do { __builtin_amdgcn_s_setprio(0); SBAR(); } while (0)
#define PH_END6() do { __builtin_amdgcn_s_setprio(0); WVM6(); SBAR(); } while (0)

// MODE 0: bf16 out = acc + bias[n];  MODE 1: bf16 out = mask?sigmoid(acc):0;
// MODE 2: f32 out = acc
template <int MODE>
__global__ void __launch_bounds__(512, 2)
gemm8p_kernel(const bf16_t* __restrict__ A, const bf16_t* __restrict__ B,
              const float* __restrict__ bias, const int* __restrict__ mask,
              void* __restrict__ Cout, int M, int N, int K,
              long sA, long sB, long sC, long sMask) {
  __shared__ __align__(1024) char smem[131072];
  const int bz = blockIdx.z;
  const bf16_t* Ab = A + bz * sA;
  const bf16_t* Bb = B + bz * sB;
  const int bm = blockIdx.x * 256, bn = blockIdx.y * 256;
  const int tid = threadIdx.x;
  const int wave = tid >> 6, lane = tid & 63;
  const int wr = wave >> 2, wc = wave & 3;
  const int l15 = lane & 15, lg = lane >> 4;
  const int xk0 = (lg * 16) ^ ((lane & 7) << 4);
  const int NT = K >> 6;

  // ds_read base offsets (slot/mh/nh added at call sites; all compile-time there)
  const int aoff = wr * 16384 + l15 * 128;           // + slot*65536 + mh*8192
  const int boff = 32768 + wc * 8192 + l15 * 128;    // + slot*65536 + nh*4096

  f32x4 acc[8][4] = {};
  bf16x8 af[8], bf_[4];

  // ---- prologue: tile0 (A0,B0,B1,A1 = 8 loads) + tile1 (A0,B1,A1 = 6 loads) ----
  stage_A(smem, Ab, K, bm, 0, 0, 0, tid);
  stage_B(smem, Bb, K, bn, 0, 0, 0, tid);
  stage_B(smem, Bb, K, bn, 0, 1, 0, tid);
  stage_A(smem, Ab, K, bm, 0, 1, 0, tid);
  stage_A(smem, Ab, K, bm, 1, 0, 64, tid);
  stage_B(smem, Bb, K, bn, 1, 1, 64, tid);
  stage_A(smem, Ab, K, bm, 1, 1, 64, tid);
  WVM6();   // tile0 fully landed (first 8 loads)
  SBAR();

  // ---- main loop: compute tiles tp,tp+1; stage tp+2,tp+3 ----
  int tp = 0;
  for (; tp + 3 < NT; tp += 2) {
    const int kb = (tp + 1) << 6, kc = (tp + 2) << 6, kd = (tp + 3) << 6;
    // P1 (tile tp, slot0, q00)
    read_A(smem, aoff + 0, af, xk0);
    read_B(smem, boff + 0, bf_, xk0);
    stage_B(smem, Bb, K, bn, 1, 0, kb, tid);
    PH_MID(); mfma_q<0, 0>(af, bf_, acc); PH_END();
    // P2 (q01)
    read_B(smem, boff + 4096, bf_, xk0);
    stage_A(smem, Ab, K, bm, 0, 0, kc, tid);
    PH_MID(); mfma_q<0, 1>(af, bf_, acc); PH_END();
    // P3 (q11)
    read_A(smem, aoff + 8192, af, xk0);
    stage_B(smem, Bb, K, bn, 0, 1, kc, tid);
    PH_MID(); mfma_q<1, 1>(af, bf_, acc); PH_END();
    // P4 (q10)
    read_B(smem, boff + 0, bf_, xk0);
    stage_A(smem, Ab, K, bm, 0, 1, kc, tid);
    PH_MID(); mfma_q<1, 0>(af, bf_, acc); PH_END6();
    // P5 (tile tp+1, slot1, q00)
    read_A(smem, aoff + 65536, af, xk0);
    read_B(smem, boff + 65536, bf_, xk0);
    stage_B(smem, Bb, K, bn, 0, 0, kc, tid);
    PH_MID(); mfma_q<0, 0>(af, bf_, acc); PH_END();
    // P6 (q01)
    read_B(smem, boff + 65536 + 4096, bf_, xk0);
    stage_A(smem, Ab, K, bm, 1, 0, kd, tid);
    PH_MID(); mfma_q<0, 1>(af, bf_, acc); PH_END();
    // P7 (q11)
    read_A(smem, aoff + 65536 + 8192, af, xk0);
    stage_B(smem, Bb, K, bn, 1, 1, kd, tid);
    PH_MID(); mfma_q<1, 1>(af, bf_, acc); PH_END();
    // P8 (q10)
    read_B(smem, boff + 65536, bf_, xk0);
    stage_A(smem, Ab, K, bm, 1, 1, kd, tid);
    PH_MID(); mfma_q<1, 0>(af, bf_, acc); PH_END6();
  }

  // ---- epilogue iteration: tiles NT-2 (slot0), NT-1 (slot1); only B0(NT-1) staged ----
  {
    const int kb = (NT - 1) << 6;
    read_A(smem, aoff + 0, af, xk0);
    read_B(smem, boff + 0, bf_, xk0);
    stage_B(smem, Bb, K, bn, 1, 0, kb, tid);
    PH_MID(); mfma_q<0, 0>(af, bf_, acc); PH_END();
    read_B(smem, boff + 4096, bf_, xk0);
    PH_MID(); mfma_q<0, 1>(af, bf_, acc); PH_END();
    read_A(smem, aoff + 8192, af, xk0);
    PH_MID(); mfma_q<1, 1>(af, bf_, acc); PH_END();
    read_B(smem, boff + 0, bf_, xk0);
    PH_MID(); mfma_q<1, 0>(af, bf_, acc);
    __builtin_amdgcn_s_setprio(0); WVM0(); SBAR();
    read_A(smem, aoff + 65536, af, xk0);
    read_B(smem, boff + 65536, bf_, xk0);
    PH_MID(); mfma_q<0, 0>(af, bf_, acc); PH_END();
    read_B(smem, boff + 65536 + 4096, bf_, xk0);
    PH_MID(); mfma_q<0, 1>(af, bf_, acc); PH_END();
    read_A(smem, aoff + 65536 + 8192, af, xk0);
    PH_MID(); mfma_q<1, 1>(af, bf_, acc); PH_END();
    read_B(smem, boff + 65536, bf_, xk0);
    PH_MID(); mfma_q<1, 0>(af, bf_, acc);
    __builtin_amdgcn_s_setprio(0);
  }

  // ---- C-write: 4 rounds of 64-row (2x32) LDS rearrange, coalesced I/O ----
  // (fully unrolled: acc indices must stay compile-time -- rule #20)
  float* eb = (float*)smem;
  const int lrow = tid >> 3, t7 = tid & 7;
#pragma unroll
  for (int rd = 0; rd < 4; ++rd) {
    __syncthreads();
#pragma unroll
    for (int fi = 0; fi < 2; ++fi)
#pragma unroll
      for (int nf = 0; nf < 4; ++nf)
#pragma unroll
        for (int r = 0; r < 4; ++r) {
          const int lr2 = wr * 32 + fi * 16 + lg * 4 + r;
          eb[lr2 * 256 + wc * 64 + nf * 16 + l15] = acc[rd * 2 + fi][nf][r];
        }
    __syncthreads();
    const int growt = rd * 32 + lrow + ((lrow >> 5) * 96);  // chunk map (wr0|wr1)
    const long rowbase = (long)(bm + growt) * N + bn;
#pragma unroll
    for (int q = 0; q < 8; ++q) {
      const int c4 = (q * 8 + t7) * 4;  // bank-spread LDS read, coalesced global
      const f32x4 v = *reinterpret_cast<const f32x4*>(&eb[lrow * 256 + c4]);
      if constexpr (MODE == 0) {
        const f32x4 b4 = *reinterpret_cast<const f32x4*>(bias + bn + c4);
        bf16x4 o;
        o[0] = (bf16_t)(v[0] + b4[0]); o[1] = (bf16_t)(v[1] + b4[1]);
        o[2] = (bf16_t)(v[2] + b4[2]); o[3] = (bf16_t)(v[3] + b4[3]);
        *reinterpret_cast<bf16x4*>((bf16_t*)Cout + bz * sC + rowbase + c4) = o;
      } else if constexpr (MODE == 1) {
        const int4 m4 = *reinterpret_cast<const int4*>(mask + bz * sMask + rowbase + c4);
        bf16x4 o;
        o[0] = (bf16_t)(m4.x ? 1.f / (1.f + __expf(-v[0])) : 0.f);
        o[1] = (bf16_t)(m4.y ? 1.f / (1.f + __expf(-v[1])) : 0.f);
        o[2] = (bf16_t)(m4.z ? 1.f / (1.f + __expf(-v[2])) : 0.f);
        o[3] = (bf16_t)(m4.w ? 1.f / (1.f + __expf(-v[3])) : 0.f);
        *reinterpret_cast<bf16x4*>((bf16_t*)Cout + bz * sC + rowbase + c4) = o;
      } else {
        *reinterpret_cast<f32x4*>((float*)Cout + bz * sC + rowbase + c4) = v;
      }
    }
  }
}

extern "C" void kernel_launch(void* const* d_in, const int* in_sizes, int n_in,
                              void* d_out, int out_size, void* d_ws, size_t ws_size,
                              hipStream_t stream) {
  const float* queries = (const float*)d_in[0];
  const float* values  = (const float*)d_in[1];
  const int*   mask    = (const int*)d_in[2];
  const float* Wq = (const float*)d_in[3];
  const float* bq = (const float*)d_in[4];
  const float* Wk = (const float*)d_in[5];
  const float* bk = (const float*)d_in[6];
  const float* Wv = (const float*)d_in[7];
  const float* bv = (const float*)d_in[8];

  // B=8, L=2048, D=768. Workspace layout (bytes):
  char* ws = (char*)d_ws;
  bf16_t* qb  = (bf16_t*)(ws + 0);          // queries bf16   25165824
  bf16_t* vb  = (bf16_t*)(ws + 25165824);   // values bf16    25165824
  bf16_t* wqb = (bf16_t*)(ws + 50331648);   // Wq bf16         1179648
  bf16_t* wkb = (bf16_t*)(ws + 51511296);   // Wk bf16         1179648
  bf16_t* wvb = (bf16_t*)(ws + 52690944);   // Wv bf16         1179648
  bf16_t* qp  = (bf16_t*)(ws + 53870592);   // q_proj         25165824
  bf16_t* vp  = (bf16_t*)(ws + 79036416);   // v_proj         25165824
  bf16_t* kp  = (bf16_t*)(ws + 104202240);  // k_proj         25165824
  bf16_t* vpT = (bf16_t*)(ws + 129368064);  // v_proj^T       25165824
  bf16_t* P   = (bf16_t*)(ws + 154533888);  // sigmoid scores 67108864

  const dim3 blk2(512);

  // converts
  f32_to_bf16_kernel<<<12288, 256, 0, stream>>>(queries, qb, 3145728);
  f32_to_bf16_kernel<<<12288, 256, 0, stream>>>(values, vb, 3145728);
  f32_to_bf16_kernel<<<576, 256, 0, stream>>>(Wq, wqb, 147456);
  f32_to_bf16_kernel<<<576, 256, 0, stream>>>(Wk, wkb, 147456);
  f32_to_bf16_kernel<<<576, 256, 0, stream>>>(Wv, wvb, 147456);

  // projections: [16384,768] x W[768,768]^T + b -> bf16
  gemm8p_kernel<0><<<dim3(64, 3, 1), blk2, 0, stream>>>(
      qb, wqb, bq, nullptr, qp, 16384, 768, 768, 0, 0, 0, 0);
  gemm8p_kernel<0><<<dim3(64, 3, 1), blk2, 0, stream>>>(
      vb, wvb, bv, nullptr, vp, 16384, 768, 768, 0, 0, 0, 0);
  // NOTE faithful quirk: k = Linear_k(v_proj)
  gemm8p_kernel<0><<<dim3(64, 3, 1), blk2, 0, stream>>>(
      vp, wkb, bk, nullptr, kp, 16384, 768, 768, 0, 0, 0, 0);

  // v_proj [b][2048][768] -> v_projT [b][768][2048]
  transpose_bf16_kernel<<<dim3(32, 12, 8), 256, 0, stream>>>(vp, vpT, 2048, 768);

  // P = sigmoid(mask(q k^T)) : per batch [2048,2048], K=768
  gemm8p_kernel<1><<<dim3(8, 8, 8), blk2, 0, stream>>>(
      qp, kp, nullptr, mask, P, 2048, 2048, 768,
      (long)2048 * 768, (long)2048 * 768, (long)2048 * 2048, (long)2048 * 2048);

  // context = P v : per batch [2048,768], K=2048, fp32 out
  gemm8p_kernel<2><<<dim3(8, 3, 8), blk2, 0, stream>>>(
      P, vpT, nullptr, nullptr, d_out, 2048, 768, 2048,
      (long)2048 * 2048, (long)768 * 2048, (long)2048 * 768, 0);
}

// Round 5
// 303.182 us; speedup vs baseline: 6.7550x; 1.0123x over previous
//
#include <hip/hip_runtime.h>
#include <hip/hip_bf16.h>

typedef __bf16 bf16_t;
typedef __bf16 bf16x8 __attribute__((ext_vector_type(8)));
typedef __bf16 bf16x4 __attribute__((ext_vector_type(4)));
typedef float  f32x4  __attribute__((ext_vector_type(4)));

#define LDS_DST(p) ((__attribute__((address_space(3))) void*)(p))
#define GLB_SRC(p) ((const __attribute__((address_space(1))) void*)(p))

#define SBAR()   asm volatile("s_barrier" ::: "memory")
#define WVM6()   asm volatile("s_waitcnt vmcnt(6)" ::: "memory")
#define WVM0()   asm volatile("s_waitcnt vmcnt(0)" ::: "memory")
#define SP1()    __builtin_amdgcn_s_setprio(1)
#define SP0()    __builtin_amdgcn_s_setprio(0)

// ---------------- fp32 -> bf16 convert ----------------
__global__ void __launch_bounds__(256)
f32_to_bf16_kernel(const float* __restrict__ in, bf16_t* __restrict__ out, int n4) {
  int i = blockIdx.x * 256 + threadIdx.x;
  if (i < n4) {
    const float4 v = reinterpret_cast<const float4*>(in)[i];
    bf16x4 o;
    o[0] = (bf16_t)v.x; o[1] = (bf16_t)v.y; o[2] = (bf16_t)v.z; o[3] = (bf16_t)v.w;
    reinterpret_cast<bf16x4*>(out)[i] = o;
  }
}

// ---------------- mask int32 -> bitmask (bit i of word w = element w*32+i) ----
// wave packs 512 consecutive ints via 8 coalesced loads + 8 ballots.
__global__ void __launch_bounds__(256)
mask_pack_kernel(const int* __restrict__ mask, unsigned long long* __restrict__ bits) {
  const long wid = (((long)blockIdx.x * 256 + threadIdx.x) >> 6);
  const int lane = threadIdx.x & 63;
  const long base = wid * 512;
  unsigned long long b[8];
#pragma unroll
  for (int i = 0; i < 8; ++i) {
    const int m = mask[base + i * 64 + lane];
    b[i] = __ballot(m != 0);
  }
  if (lane == 0) {
    unsigned long long* o = bits + wid * 8;
#pragma unroll
    for (int i = 0; i < 8; ++i) o[i] = b[i];
  }
}

// ---------------- bf16 transpose: in [z][R][C] -> out [z][C][R] ----------------
__global__ void __launch_bounds__(256)
transpose_bf16_kernel(const bf16_t* __restrict__ in, bf16_t* __restrict__ out,
                      int R, int C) {
  __shared__ bf16_t tile[64][72];
  const long base = (long)blockIdx.z * R * C;
  const bf16_t* ib = in + base;
  bf16_t* ob = out + base;
  const int r0 = blockIdx.x * 64, c0 = blockIdx.y * 64;
  const int tid = threadIdx.x;
  const int rr = tid >> 3, cg = tid & 7;
#pragma unroll
  for (int p = 0; p < 2; ++p) {
    int row = p * 32 + rr;
    bf16x8 v = *reinterpret_cast<const bf16x8*>(ib + (long)(r0 + row) * C + c0 + cg * 8);
    *reinterpret_cast<bf16x8*>(&tile[row][cg * 8]) = v;
  }
  __syncthreads();
#pragma unroll
  for (int p = 0; p < 2; ++p) {
    int c = p * 32 + rr;
    bf16x8 v;
#pragma unroll
    for (int i = 0; i < 8; ++i) v[i] = tile[cg * 8 + i][c];
    *reinterpret_cast<bf16x8*>(ob + (long)(c0 + c) * R + r0 + cg * 8) = v;
  }
}

// ================= 256x256 8-phase GEMM (T2+T3+T4+T5) =================
// Single barrier per phase: cross-wave staging visibility comes from the
// vmcnt(6)+SBAR checkpoints at P4/P8; read-before-overwrite from "stage(p+1)
// issued after SBAR(p)". The pre-MFMA barrier (round 4) only created a
// lockstep convoy (all waves ds_read together, all MFMA together) -- removed.
// Staging map (phase p stages the region last read at p-1, 2 tiles ahead):
//   P1: B0(t+1->s1)  P2: A0(t+2->s0)  P3: B1(t+2->s0)  P4: A1(t+2->s0) vmcnt(6)
//   P5: B0(t+2->s0)  P6: A0(t+3->s1)  P7: B1(t+3->s1)  P8: A1(t+3->s1) vmcnt(6)

__device__ __forceinline__ void stage_A(char* smem, const bf16_t* G, int ldK,
                                        int grow0, int slot, int mh, int kt, int tid) {
  const int wave = tid >> 6, l = tid & 63;
  const int lr = l >> 3;
  const int cgs = ((l & 7) ^ lr) * 8;       // pre-swizzled source col-group (rule #21)
#pragma unroll
  for (int j = 0; j < 2; ++j) {
    const int rowbase = j * 128 + mh * 64 + wave * 8;
    __builtin_amdgcn_global_load_lds(
        GLB_SRC(G + (long)(grow0 + rowbase + lr) * ldK + kt + cgs),
        LDS_DST(smem + slot * 65536 + rowbase * 128), 16, 0, 0);
  }
}

__device__ __forceinline__ void stage_B(char* smem, const bf16_t* G, int ldK,
                                        int grow0, int slot, int nh, int kt, int tid) {
  const int wave = tid >> 6, l = tid & 63;
  const int lr = l >> 3;
  const int cgs = ((l & 7) ^ lr) * 8;
#pragma unroll
  for (int j = 0; j < 2; ++j) {
    const int c = wave + j * 8;
    const int rowbase = (c >> 2) * 64 + nh * 32 + (c & 3) * 8;
    __builtin_amdgcn_global_load_lds(
        GLB_SRC(G + (long)(grow0 + rowbase + lr) * ldK + kt + cgs),
        LDS_DST(smem + slot * 65536 + 32768 + rowbase * 128), 16, 0, 0);
  }
}

__device__ __forceinline__ void read_A(const char* smem, int off, bf16x8 (&af)[8], int xk0) {
#pragma unroll
  for (int mf = 0; mf < 4; ++mf)
#pragma unroll
    for (int kk = 0; kk < 2; ++kk)
      af[mf * 2 + kk] = *reinterpret_cast<const bf16x8*>(
          smem + off + mf * 2048 + (kk ? (xk0 ^ 64) : xk0));
}

__device__ __forceinline__ void read_B(const char* smem, int off, bf16x8 (&bf_)[4], int xk0) {
#pragma unroll
  for (int nf = 0; nf < 2; ++nf)
#pragma unroll
    for (int kk = 0; kk < 2; ++kk)
      bf_[nf * 2 + kk] = *reinterpret_cast<const bf16x8*>(
          smem + off + nf * 2048 + (kk ? (xk0 ^ 64) : xk0));
}

template <int MH, int NH>
__device__ __forceinline__ void mfma_q(const bf16x8 (&af)[8], const bf16x8 (&bf_)[4],
                                       f32x4 (&acc)[8][4]) {
#pragma unroll
  for (int mf = 0; mf < 4; ++mf)
#pragma unroll
    for (int nf = 0; nf < 2; ++nf)
#pragma unroll
      for (int kk = 0; kk < 2; ++kk)
        acc[MH * 4 + mf][NH * 2 + nf] = __builtin_amdgcn_mfma_f32_16x16x32_bf16(
            af[mf * 2 + kk], bf_[nf * 2 + kk], acc[MH * 4 + mf][NH * 2 + nf], 0, 0, 0);
}

// MODE 0: bf16 out = acc + bias[n];  MODE 1: bf16 out = maskbit?sigmoid(acc):0;
// MODE 2: f32 out = acc
template <int MODE>
__global__ void __launch_bounds__(512, 2)
gemm8p_kernel(const bf16_t* __restrict__ A, const bf16_t* __restrict__ B,
              const float* __restrict__ bias, const unsigned* __restrict__ maskbits,
              void* __restrict__ Cout, int M, int N, int K,
              long sA, long sB, long sC, long sMask) {
  __shared__ __align__(1024) char smem[131072];
  const int bz = blockIdx.z;
  const bf16_t* Ab = A + bz * sA;
  const bf16_t* Bb = B + bz * sB;
  const int bm = blockIdx.x * 256, bn = blockIdx.y * 256;
  const int tid = threadIdx.x;
  const int wave = tid >> 6, lane = tid & 63;
  const int wr = wave >> 2, wc = wave & 3;
  const int l15 = lane & 15, lg = lane >> 4;
  const int xk0 = (lg * 16) ^ ((lane & 7) << 4);
  const int NT = K >> 6;

  const int aoff = wr * 16384 + l15 * 128;
  const int boff = 32768 + wc * 8192 + l15 * 128;

  f32x4 acc[8][4] = {};
  bf16x8 af[8], bf_[4];

  // ---- prologue: tile0->s0 (8 loads) + tile1->s1 partial (6 loads) ----
  stage_A(smem, Ab, K, bm, 0, 0, 0, tid);
  stage_B(smem, Bb, K, bn, 0, 0, 0, tid);
  stage_B(smem, Bb, K, bn, 0, 1, 0, tid);
  stage_A(smem, Ab, K, bm, 0, 1, 0, tid);
  stage_A(smem, Ab, K, bm, 1, 0, 64, tid);
  stage_B(smem, Bb, K, bn, 1, 1, 64, tid);
  stage_A(smem, Ab, K, bm, 1, 1, 64, tid);
  WVM6();   // tile0's 8 loads landed
  SBAR();

  int tp = 0;
  for (; tp + 3 < NT; tp += 2) {
    const int kb = (tp + 1) << 6, kc = (tp + 2) << 6, kd = (tp + 3) << 6;
    // P1 (tile tp, slot0, q00)
    read_A(smem, aoff + 0, af, xk0);
    read_B(smem, boff + 0, bf_, xk0);
    stage_B(smem, Bb, K, bn, 1, 0, kb, tid);
    SP1(); mfma_q<0, 0>(af, bf_, acc); SP0(); SBAR();
    // P2 (q01)
    read_B(smem, boff + 4096, bf_, xk0);
    stage_A(smem, Ab, K, bm, 0, 0, kc, tid);
    SP1(); mfma_q<0, 1>(af, bf_, acc); SP0(); SBAR();
    // P3 (q11)
    read_A(smem, aoff + 8192, af, xk0);
    stage_B(smem, Bb, K, bn, 0, 1, kc, tid);
    SP1(); mfma_q<1, 1>(af, bf_, acc); SP0(); SBAR();
    // P4 (q10)
    read_B(smem, boff + 0, bf_, xk0);
    stage_A(smem, Ab, K, bm, 0, 1, kc, tid);
    SP1(); mfma_q<1, 0>(af, bf_, acc); SP0(); WVM6(); SBAR();
    // P5 (tile tp+1, slot1, q00)
    read_A(smem, aoff + 65536, af, xk0);
    read_B(smem, boff + 65536, bf_, xk0);
    stage_B(smem, Bb, K, bn, 0, 0, kc, tid);
    SP1(); mfma_q<0, 0>(af, bf_, acc); SP0(); SBAR();
    // P6 (q01)
    read_B(smem, boff + 65536 + 4096, bf_, xk0);
    stage_A(smem, Ab, K, bm, 1, 0, kd, tid);
    SP1(); mfma_q<0, 1>(af, bf_, acc); SP0(); SBAR();
    // P7 (q11)
    read_A(smem, aoff + 65536 + 8192, af, xk0);
    stage_B(smem, Bb, K, bn, 1, 1, kd, tid);
    SP1(); mfma_q<1, 1>(af, bf_, acc); SP0(); SBAR();
    // P8 (q10)
    read_B(smem, boff + 65536, bf_, xk0);
    stage_A(smem, Ab, K, bm, 1, 1, kd, tid);
    SP1(); mfma_q<1, 0>(af, bf_, acc); SP0(); WVM6(); SBAR();
  }

  // ---- final two tiles: NT-2 (slot0), NT-1 (slot1); only B0(NT-1) to stage ----
  {
    const int kb = (NT - 1) << 6;
    read_A(smem, aoff + 0, af, xk0);
    read_B(smem, boff + 0, bf_, xk0);
    stage_B(smem, Bb, K, bn, 1, 0, kb, tid);
    SP1(); mfma_q<0, 0>(af, bf_, acc); SP0(); SBAR();
    read_B(smem, boff + 4096, bf_, xk0);
    SP1(); mfma_q<0, 1>(af, bf_, acc); SP0(); SBAR();
    read_A(smem, aoff + 8192, af, xk0);
    SP1(); mfma_q<1, 1>(af, bf_, acc); SP0(); SBAR();
    read_B(smem, boff + 0, bf_, xk0);
    SP1(); mfma_q<1, 0>(af, bf_, acc); SP0(); WVM0(); SBAR();
    read_A(smem, aoff + 65536, af, xk0);
    read_B(smem, boff + 65536, bf_, xk0);
    SP1(); mfma_q<0, 0>(af, bf_, acc); SP0(); SBAR();
    read_B(smem, boff + 65536 + 4096, bf_, xk0);
    SP1(); mfma_q<0, 1>(af, bf_, acc); SP0(); SBAR();
    read_A(smem, aoff + 65536 + 8192, af, xk0);
    SP1(); mfma_q<1, 1>(af, bf_, acc); SP0(); SBAR();
    read_B(smem, boff + 65536, bf_, xk0);
    SP1(); mfma_q<1, 0>(af, bf_, acc); SP0();
  }

  // ---- C-write: 4 rounds of 64-row LDS rearrange, coalesced I/O ----
  // (fully unrolled: acc indices must stay compile-time -- rule #20)
  float* eb = (float*)smem;
  const int lrow = tid >> 3, t7 = tid & 7;
#pragma unroll
  for (int rd = 0; rd < 4; ++rd) {
    __syncthreads();
#pragma unroll
    for (int fi = 0; fi < 2; ++fi)
#pragma unroll
      for (int nf = 0; nf < 4; ++nf)
#pragma unroll
        for (int r = 0; r < 4; ++r) {
          const int lr2 = wr * 32 + fi * 16 + lg * 4 + r;
          eb[lr2 * 256 + wc * 64 + nf * 16 + l15] = acc[rd * 2 + fi][nf][r];
        }
    __syncthreads();
    const int growt = rd * 32 + lrow + ((lrow >> 5) * 96);
    const long rowbase = (long)(bm + growt) * N + bn;
    if constexpr (MODE == 1) {
      // packed mask: 8 u32 words cover this row's 256-col block (broadcast loads)
      const unsigned* mw =
          maskbits + bz * sMask + (long)(bm + growt) * (N >> 5) + (bn >> 5);
      const uint4 w0 = *reinterpret_cast<const uint4*>(mw);
      const uint4 w1 = *reinterpret_cast<const uint4*>(mw + 4);
      const unsigned wq[8] = {w0.x, w0.y, w0.z, w0.w, w1.x, w1.y, w1.z, w1.w};
#pragma unroll
      for (int q = 0; q < 8; ++q) {
        const int c4 = (q * 8 + t7) * 4;
        const f32x4 v = *reinterpret_cast<const f32x4*>(&eb[lrow * 256 + c4]);
        const unsigned nib = (wq[q] >> (t7 * 4)) & 0xFu;
        bf16x4 o;
        o[0] = (bf16_t)((nib & 1u) ? 1.f / (1.f + __expf(-v[0])) : 0.f);
        o[1] = (bf16_t)((nib & 2u) ? 1.f / (1.f + __expf(-v[1])) : 0.f);
        o[2] = (bf16_t)((nib & 4u) ? 1.f / (1.f + __expf(-v[2])) : 0.f);
        o[3] = (bf16_t)((nib & 8u) ? 1.f / (1.f + __expf(-v[3])) : 0.f);
        *reinterpret_cast<bf16x4*>((bf16_t*)Cout + bz * sC + rowbase + c4) = o;
      }
    } else {
#pragma unroll
      for (int q = 0; q < 8; ++q) {
        const int c4 = (q * 8 + t7) * 4;
        const f32x4 v = *reinterpret_cast<const f32x4*>(&eb[lrow * 256 + c4]);
        if constexpr (MODE == 0) {
          const f32x4 b4 = *reinterpret_cast<const f32x4*>(bias + bn + c4);
          bf16x4 o;
          o[0] = (bf16_t)(v[0] + b4[0]); o[1] = (bf16_t)(v[1] + b4[1]);
          o[2] = (bf16_t)(v[2] + b4[2]); o[3] = (bf16_t)(v[3] + b4[3]);
          *reinterpret_cast<bf16x4*>((bf16_t*)Cout + bz * sC + rowbase + c4) = o;
        } else {
          *reinterpret_cast<f32x4*>((float*)Cout + bz * sC + rowbase + c4) = v;
        }
      }
    }
  }
}

extern "C" void kernel_launch(void* const* d_in, const int* in_sizes, int n_in,
                              void* d_out, int out_size, void* d_ws, size_t ws_size,
                              hipStream_t stream) {
  const float* queries = (const float*)d_in[0];
  const float* values  = (const float*)d_in[1];
  const int*   mask    = (const int*)d_in[2];
  const float* Wq = (const float*)d_in[3];
  const float* bq = (const float*)d_in[4];
  const float* Wk = (const float*)d_in[5];
  const float* bk = (const float*)d_in[6];
  const float* Wv = (const float*)d_in[7];
  const float* bv = (const float*)d_in[8];

  // B=8, L=2048, D=768. Workspace layout (bytes):
  char* ws = (char*)d_ws;
  bf16_t* qb  = (bf16_t*)(ws + 0);          // queries bf16   25165824
  bf16_t* vb  = (bf16_t*)(ws + 25165824);   // values bf16    25165824
  bf16_t* wqb = (bf16_t*)(ws + 50331648);   // Wq bf16         1179648
  bf16_t* wkb = (bf16_t*)(ws + 51511296);   // Wk bf16         1179648
  bf16_t* wvb = (bf16_t*)(ws + 52690944);   // Wv bf16         1179648
  bf16_t* qp  = (bf16_t*)(ws + 53870592);   // q_proj         25165824
  bf16_t* vp  = (bf16_t*)(ws + 79036416);   // v_proj         25165824
  bf16_t* kp  = (bf16_t*)(ws + 104202240);  // k_proj         25165824
  bf16_t* vpT = (bf16_t*)(ws + 129368064);  // v_proj^T       25165824
  bf16_t* P   = (bf16_t*)(ws + 154533888);  // sigmoid scores 67108864
  unsigned long long* mbits = (unsigned long long*)(ws + 221642752);  // 4194304
  // total: 225837056

  // mask pack: 33.55M ints / 512 per wave = 65536 waves = 16384 blocks
  mask_pack_kernel<<<16384, 256, 0, stream>>>(mask, mbits);

  // converts
  f32_to_bf16_kernel<<<12288, 256, 0, stream>>>(queries, qb, 3145728);
  f32_to_bf16_kernel<<<12288, 256, 0, stream>>>(values, vb, 3145728);
  f32_to_bf16_kernel<<<576, 256, 0, stream>>>(Wq, wqb, 147456);
  f32_to_bf16_kernel<<<576, 256, 0, stream>>>(Wk, wkb, 147456);
  f32_to_bf16_kernel<<<576, 256, 0, stream>>>(Wv, wvb, 147456);

  const dim3 blk2(512);

  // projections: [16384,768] x W[768,768]^T + b -> bf16
  gemm8p_kernel<0><<<dim3(64, 3, 1), blk2, 0, stream>>>(
      qb, wqb, bq, nullptr, qp, 16384, 768, 768, 0, 0, 0, 0);
  gemm8p_kernel<0><<<dim3(64, 3, 1), blk2, 0, stream>>>(
      vb, wvb, bv, nullptr, vp, 16384, 768, 768, 0, 0, 0, 0);
  // NOTE faithful quirk: k = Linear_k(v_proj)
  gemm8p_kernel<0><<<dim3(64, 3, 1), blk2, 0, stream>>>(
      vp, wkb, bk, nullptr, kp, 16384, 768, 768, 0, 0, 0, 0);

  // v_proj [b][2048][768] -> v_projT [b][768][2048]
  transpose_bf16_kernel<<<dim3(32, 12, 8), 256, 0, stream>>>(vp, vpT, 2048, 768);

  // P = sigmoid(mask(q k^T)) : per batch [2048,2048], K=768; mask = packed bits
  gemm8p_kernel<1><<<dim3(8, 8, 8), blk2, 0, stream>>>(
      qp, kp, nullptr, (const unsigned*)mbits, P, 2048, 2048, 768,
      (long)2048 * 768, (long)2048 * 768, (long)2048 * 2048, (long)2048 * 64);

  // context = P v : per batch [2048,768], K=2048, fp32 out
  gemm8p_kernel<2><<<dim3(8, 3, 8), blk2, 0, stream>>>(
      P, vpT, nullptr, nullptr, d_out, 2048, 768, 2048,
      (long)2048 * 2048, (long)768 * 2048, (long)2048 * 768, 0);
}